// Round 9
// baseline (421.087 us; speedup 1.0000x reference)
//
#include <hip/hip_runtime.h>

constexpr int NN = 100000;   // nodes
constexpr int NE = 1600000;  // edges
constexpr int DI = 256, DH = 128, DO = 40;

// Bucket radix sort params
constexpr int NB = (NN + 255) >> 8;        // 391 buckets of 256 dst values
constexpr int NB_BLK = 128;                // blocks in hist/scatter passes
constexpr int CHUNK = NE / NB_BLK;         // 12500 edges per block (exact)
constexpr int M2 = NB * NB_BLK;            // 50048 hist entries
constexpr int NBS = (M2 + 1023) / 1024;    // 49 scan partials
constexpr int STAGE_CAP = 6144;            // bucket staging (avg load ~4092)

typedef __attribute__((ext_vector_type(8))) __bf16 bf16x8;
typedef __attribute__((ext_vector_type(4))) float f32x4;

__device__ inline float4 bf4_to_f4(ushort4 u) {
    return make_float4(__builtin_bit_cast(float, (unsigned)u.x << 16),
                       __builtin_bit_cast(float, (unsigned)u.y << 16),
                       __builtin_bit_cast(float, (unsigned)u.z << 16),
                       __builtin_bit_cast(float, (unsigned)u.w << 16));
}
__device__ inline unsigned short f2bf(float f) {
    return __builtin_bit_cast(unsigned short, (__bf16)f);   // RNE
}
__device__ inline bf16x8 bf16x8_zero() {
    bf16x8 r;
    #pragma unroll
    for (int j = 0; j < 8; ++j) r[j] = (__bf16)0.f;
    return r;
}
__device__ inline bf16x8 load_cvt_a(const float* __restrict__ p, bool ok) {
    if (!ok) return bf16x8_zero();
    bf16x8 r;
    const float4 v0 = *(const float4*)p;
    const float4 v1 = *(const float4*)(p + 4);
    r[0] = (__bf16)v0.x; r[1] = (__bf16)v0.y; r[2] = (__bf16)v0.z; r[3] = (__bf16)v0.w;
    r[4] = (__bf16)v1.x; r[5] = (__bf16)v1.y; r[6] = (__bf16)v1.z; r[7] = (__bf16)v1.w;
    return r;
}

// ---------------- W1 pack: W1[256,128] f32 -> Wf in MFMA B-frag order ----------------
// Wf[((kt*8+nt)*64+lane)*8+j] = W1[k][n], k=kt*32+(lane>>4)*8+j, n=nt*16+(lane&15).
__global__ __launch_bounds__(256) void w1pack_kernel(const float* __restrict__ W,
                                                     __bf16* __restrict__ Wf) {
    const int i = blockIdx.x * 256 + threadIdx.x;   // 32768 total
    const int j = i & 7;
    const int lane = (i >> 3) & 63;
    const int nt = (i >> 9) & 7;
    const int kt = i >> 12;
    const int k = kt * 32 + (lane >> 4) * 8 + j;
    const int n = nt * 16 + (lane & 15);
    Wf[i] = (__bf16)W[(size_t)k * DH + n];
}

// ---------------- W2 pack: W2[128,40] f32 -> Wf2 in B-frag order (N padded to 48) -----
// Wf2[((ks*3+nt)*64+lane)*8+j] = W2[k][n] (0 if n>=40), k=ks*32+(lane>>4)*8+j, n=nt*16+(lane&15)
__global__ __launch_bounds__(256) void w2pack_kernel(const float* __restrict__ W2,
                                                     __bf16* __restrict__ Wf2) {
    const int i = blockIdx.x * 256 + threadIdx.x;   // 6144 total
    const int j = i & 7;
    const int lane = (i >> 3) & 63;
    const int g = i >> 9;          // 0..11
    const int nt = g % 3, ks = g / 3;
    const int k = ks * 32 + (lane >> 4) * 8 + j;
    const int n = nt * 16 + (lane & 15);
    Wf2[i] = (n < DO) ? (__bf16)W2[(size_t)k * DO + n] : (__bf16)0.f;
}

// ---------------- GEMM1 (bf16 MFMA, no LDS, no barriers) ----------------
__global__ __launch_bounds__(256) void gemm1_kernel(const float* __restrict__ x,
                                                    const __bf16* __restrict__ Wf,
                                                    __bf16* __restrict__ h1) {
    const int t = threadIdx.x;
    const int wave = t >> 6, lane = t & 63;
    const int q = lane >> 4, m = lane & 15;
    const int row0 = blockIdx.x * 64 + wave * 16;
    const int r = row0 + m;
    const bool ok = r < NN;
    const float* xp = x + (size_t)r * DI;

    bf16x8 a[8];
    #pragma unroll
    for (int kt = 0; kt < 8; ++kt)
        a[kt] = load_cvt_a(xp + kt * 32 + q * 8, ok);

    f32x4 acc[8];
    #pragma unroll
    for (int nt = 0; nt < 8; ++nt)
        #pragma unroll
        for (int rr = 0; rr < 4; ++rr) acc[nt][rr] = 0.f;

    const bf16x8* wf = (const bf16x8*)Wf;
    #pragma unroll
    for (int kt = 0; kt < 8; ++kt) {
        #pragma unroll
        for (int nt = 0; nt < 8; ++nt) {
            const bf16x8 b = wf[(kt * 8 + nt) * 64 + lane];
            acc[nt] = __builtin_amdgcn_mfma_f32_16x16x32_bf16(a[kt], b, acc[nt], 0, 0, 0);
        }
    }
    #pragma unroll
    for (int reg = 0; reg < 4; ++reg) {
        const int rr = row0 + q * 4 + reg;
        if (rr < NN) {
            __bf16* hp = h1 + (size_t)rr * DH + m;
            #pragma unroll
            for (int nt = 0; nt < 8; ++nt) hp[nt * 16] = (__bf16)acc[nt][reg];
        }
    }
}

// ---------------- P1: per-block bucket histogram ----------------
__global__ __launch_bounds__(256) void bucket_hist_kernel(const int* __restrict__ dst,
                                                          int* __restrict__ hist2d) {
    __shared__ int h[NB];
    for (int i = threadIdx.x; i < NB; i += 256) h[i] = 0;
    __syncthreads();
    const int base = blockIdx.x * CHUNK;
    for (int i = threadIdx.x; i < CHUNK; i += 256)
        atomicAdd(&h[dst[base + i] >> 8], 1);
    __syncthreads();
    for (int i = threadIdx.x; i < NB; i += 256)
        hist2d[i * NB_BLK + blockIdx.x] = h[i];   // bucket-major
}

// ---------------- scan of hist2d (M2 entries) ----------------
__global__ __launch_bounds__(256) void spart_kernel(const int* __restrict__ in,
                                                    int* __restrict__ bsum) {
    __shared__ int red[256];
    const int idx = blockIdx.x * 1024 + threadIdx.x * 4;
    int s = 0;
    if (idx < M2) { const int4 v = *(const int4*)(in + idx); s = v.x + v.y + v.z + v.w; }
    red[threadIdx.x] = s;
    __syncthreads();
    #pragma unroll
    for (int d = 128; d > 0; d >>= 1) {
        if (threadIdx.x < d) red[threadIdx.x] += red[threadIdx.x + d];
        __syncthreads();
    }
    if (threadIdx.x == 0) bsum[blockIdx.x] = red[0];
}

__global__ __launch_bounds__(64) void sblock_kernel(const int* __restrict__ bsum,
                                                    int* __restrict__ boff) {
    __shared__ int part[64];
    const int t = threadIdx.x;
    const int v = (t < NBS) ? bsum[t] : 0;
    part[t] = v;
    __syncthreads();
    for (int d = 1; d < 64; d <<= 1) {
        const int u = (t >= d) ? part[t - d] : 0;
        __syncthreads();
        part[t] += u;
        __syncthreads();
    }
    if (t < NBS) boff[t] = part[t] - v;
}

__global__ __launch_bounds__(256) void sfinal_kernel(const int* __restrict__ in,
                                                     const int* __restrict__ boff,
                                                     int* __restrict__ out) {
    __shared__ int part[256];
    const int t = threadIdx.x;
    const int idx = blockIdx.x * 1024 + t * 4;
    int4 v = make_int4(0, 0, 0, 0);
    if (idx < M2) v = *(const int4*)(in + idx);
    const int s = v.x + v.y + v.z + v.w;
    part[t] = s;
    __syncthreads();
    for (int d = 1; d < 256; d <<= 1) {
        const int u = (t >= d) ? part[t - d] : 0;
        __syncthreads();
        part[t] += u;
        __syncthreads();
    }
    if (idx < M2) {
        const int base = boff[blockIdx.x] + part[t] - s;
        *(int4*)(out + idx) = make_int4(base, base + v.x, base + v.x + v.y,
                                        base + v.x + v.y + v.z);
    }
}

// ---------------- P3: scatter packed (src | dstbyte<<24) into bucket partitions -------
__global__ __launch_bounds__(256) void bucket_scatter_kernel(const int* __restrict__ src,
                                                             const int* __restrict__ dst,
                                                             const int* __restrict__ offs2d,
                                                             unsigned* __restrict__ epack) {
    __shared__ int cur[NB];
    for (int i = threadIdx.x; i < NB; i += 256)
        cur[i] = offs2d[i * NB_BLK + blockIdx.x];
    __syncthreads();
    const int base = blockIdx.x * CHUNK;
    for (int i = threadIdx.x; i < CHUNK; i += 256) {
        const int d = dst[base + i], s = src[base + i];
        const int p = atomicAdd(&cur[d >> 8], 1);
        epack[p] = (unsigned)s | ((unsigned)(d & 255) << 24);
    }
}

// ---------------- P4: within-bucket counting sort; emits off[] and esrc ----------------
__global__ __launch_bounds__(256) void bucket_sort_kernel(const unsigned* __restrict__ epack,
                                                          const int* __restrict__ offs2d,
                                                          int* __restrict__ off,
                                                          int* __restrict__ esrc) {
    __shared__ int cnt[256];
    __shared__ int incl[256];
    __shared__ int cur[256];
    __shared__ int stage[STAGE_CAP];
    const int b = blockIdx.x;
    const int t = threadIdx.x;
    const int bstart = offs2d[b * NB_BLK];
    const int bend = (b + 1 < NB) ? offs2d[(b + 1) * NB_BLK] : NE;
    const int n = bend - bstart;
    cnt[t] = 0;
    __syncthreads();
    for (int i = t; i < n; i += 256)
        atomicAdd(&cnt[epack[bstart + i] >> 24], 1);
    __syncthreads();
    incl[t] = cnt[t];
    __syncthreads();
    for (int d = 1; d < 256; d <<= 1) {
        const int u = (t >= d) ? incl[t - d] : 0;
        __syncthreads();
        incl[t] += u;
        __syncthreads();
    }
    const int ex = incl[t] - cnt[t];   // exclusive prefix within bucket
    const int node = (b << 8) + t;
    if (node <= NN) off[node] = bstart + ex;   // node==NN -> off[NN]=NE
    cur[t] = ex;
    __syncthreads();
    const bool staged = (n <= STAGE_CAP);
    for (int i = t; i < n; i += 256) {
        const unsigned pk = epack[bstart + i];
        const int p = atomicAdd(&cur[pk >> 24], 1);
        const int s = (int)(pk & 0xFFFFFFu);
        if (staged) stage[p] = s;
        else esrc[bstart + p] = s;
    }
    __syncthreads();
    if (staged)
        for (int i = t; i < n; i += 256) esrc[bstart + i] = stage[i];
}

// ---------------- Fused Agg1 + GEMM2 ----------------
// h2[NN,40](bf16) = relu(sum_{e:dst=n} h1[src_e]) @ W2.
// Each wave: aggregate 16 nodes (half-wave per edge, unroll 8 -> 16 loads in
// flight), park relu'd bf16 rows in per-wave LDS tile, then 12 MFMAs with
// pre-packed Wf2 B-frags (no staging barrier needed).
__global__ __launch_bounds__(256) void agg1g2_kernel(const __bf16* __restrict__ h1,
                                                     const int* __restrict__ esrc,
                                                     const int* __restrict__ off,
                                                     const __bf16* __restrict__ Wf2,
                                                     __bf16* __restrict__ h2) {
    __shared__ __bf16 rows[4][16][136];   // 17.4 KB; per-wave private tiles
    const int t = threadIdx.x;
    const int wave = t >> 6, lane = t & 63;
    const int half = lane >> 5;
    const int c = (lane & 31) * 4;
    const int q = lane >> 4, m = lane & 15;
    const int node0 = blockIdx.x * 64 + wave * 16;

    for (int i = 0; i < 16; ++i) {
        const int n = node0 + i;
        float4 a0 = make_float4(0.f, 0.f, 0.f, 0.f);
        float4 a1 = a0, a2 = a0, a3 = a0, a4 = a0, a5 = a0, a6 = a0, a7 = a0;
        if (n < NN) {
            const int b = off[n], e = off[n + 1];
            int j = b + half;
            for (; j + 14 < e; j += 16) {
                const int s0 = esrc[j],      s1 = esrc[j + 2],  s2 = esrc[j + 4],  s3 = esrc[j + 6];
                const int s4 = esrc[j + 8],  s5 = esrc[j + 10], s6 = esrc[j + 12], s7 = esrc[j + 14];
                const float4 v0 = bf4_to_f4(*(const ushort4*)(h1 + (size_t)s0 * DH + c));
                const float4 v1 = bf4_to_f4(*(const ushort4*)(h1 + (size_t)s1 * DH + c));
                const float4 v2 = bf4_to_f4(*(const ushort4*)(h1 + (size_t)s2 * DH + c));
                const float4 v3 = bf4_to_f4(*(const ushort4*)(h1 + (size_t)s3 * DH + c));
                const float4 v4 = bf4_to_f4(*(const ushort4*)(h1 + (size_t)s4 * DH + c));
                const float4 v5 = bf4_to_f4(*(const ushort4*)(h1 + (size_t)s5 * DH + c));
                const float4 v6 = bf4_to_f4(*(const ushort4*)(h1 + (size_t)s6 * DH + c));
                const float4 v7 = bf4_to_f4(*(const ushort4*)(h1 + (size_t)s7 * DH + c));
                a0.x += v0.x; a0.y += v0.y; a0.z += v0.z; a0.w += v0.w;
                a1.x += v1.x; a1.y += v1.y; a1.z += v1.z; a1.w += v1.w;
                a2.x += v2.x; a2.y += v2.y; a2.z += v2.z; a2.w += v2.w;
                a3.x += v3.x; a3.y += v3.y; a3.z += v3.z; a3.w += v3.w;
                a4.x += v4.x; a4.y += v4.y; a4.z += v4.z; a4.w += v4.w;
                a5.x += v5.x; a5.y += v5.y; a5.z += v5.z; a5.w += v5.w;
                a6.x += v6.x; a6.y += v6.y; a6.z += v6.z; a6.w += v6.w;
                a7.x += v7.x; a7.y += v7.y; a7.z += v7.z; a7.w += v7.w;
            }
            for (; j < e; j += 2) {
                const int s = esrc[j];
                const float4 v = bf4_to_f4(*(const ushort4*)(h1 + (size_t)s * DH + c));
                a0.x += v.x; a0.y += v.y; a0.z += v.z; a0.w += v.w;
            }
        }
        float4 acc = make_float4(a0.x + a1.x + a2.x + a3.x + a4.x + a5.x + a6.x + a7.x,
                                 a0.y + a1.y + a2.y + a3.y + a4.y + a5.y + a6.y + a7.y,
                                 a0.z + a1.z + a2.z + a3.z + a4.z + a5.z + a6.z + a7.z,
                                 a0.w + a1.w + a2.w + a3.w + a4.w + a5.w + a6.w + a7.w);
        acc.x += __shfl_xor(acc.x, 32);
        acc.y += __shfl_xor(acc.y, 32);
        acc.z += __shfl_xor(acc.z, 32);
        acc.w += __shfl_xor(acc.w, 32);
        if (half == 0) {
            ushort4 o;
            o.x = f2bf(fmaxf(acc.x, 0.f));
            o.y = f2bf(fmaxf(acc.y, 0.f));
            o.z = f2bf(fmaxf(acc.z, 0.f));
            o.w = f2bf(fmaxf(acc.w, 0.f));
            *(ushort4*)(&rows[wave][i][c]) = o;
        }
    }
    __syncthreads();   // cheap: waves have near-equal work (sum of 16 degrees)

    // GEMM2 on this wave's 16-row tile: A[m][k] = rows[wave][m][k]
    f32x4 acc2[3];
    #pragma unroll
    for (int nt = 0; nt < 3; ++nt)
        #pragma unroll
        for (int rr = 0; rr < 4; ++rr) acc2[nt][rr] = 0.f;
    const bf16x8* wf2 = (const bf16x8*)Wf2;
    #pragma unroll
    for (int ks = 0; ks < 4; ++ks) {
        const int k0 = ks * 32 + q * 8;
        const bf16x8 a = *(const bf16x8*)(&rows[wave][m][k0]);
        #pragma unroll
        for (int nt = 0; nt < 3; ++nt) {
            const bf16x8 b = wf2[(ks * 3 + nt) * 64 + lane];
            acc2[nt] = __builtin_amdgcn_mfma_f32_16x16x32_bf16(a, b, acc2[nt], 0, 0, 0);
        }
    }
    #pragma unroll
    for (int reg = 0; reg < 4; ++reg) {
        const int rr = node0 + q * 4 + reg;
        if (rr < NN) {
            #pragma unroll
            for (int nt = 0; nt < 3; ++nt) {
                const int cc = nt * 16 + m;
                if (cc < DO) h2[(size_t)rr * DO + cc] = (__bf16)acc2[nt][reg];
            }
        }
    }
}

// ---------------- Agg2: out[n](f32) = sum h2[src_e], d=40 ----------------
// 10 lanes x ushort4 = one 80B row, 6 edges/iter; stride-12 unroll-2 main + tail.
__global__ __launch_bounds__(256) void agg2_kernel(const __bf16* __restrict__ h2,
                                                   const int* __restrict__ esrc,
                                                   const int* __restrict__ off,
                                                   float* __restrict__ out) {
    const int w = (blockIdx.x * 256 + threadIdx.x) >> 6;
    if (w >= NN) return;
    const int lane = threadIdx.x & 63;
    const int sub = lane / 10;          // 0..5 active, lanes 60..63 idle
    const int c = (lane % 10) * 4;
    const int b = off[w], e = off[w + 1];
    float4 a0 = make_float4(0.f, 0.f, 0.f, 0.f);
    float4 a1 = a0;
    if (sub < 6) {
        int j = b + sub;
        for (; j + 6 < e; j += 12) {
            const int s0 = esrc[j], s1 = esrc[j + 6];
            const float4 v0 = bf4_to_f4(*(const ushort4*)(h2 + (size_t)s0 * DO + c));
            const float4 v1 = bf4_to_f4(*(const ushort4*)(h2 + (size_t)s1 * DO + c));
            a0.x += v0.x; a0.y += v0.y; a0.z += v0.z; a0.w += v0.w;
            a1.x += v1.x; a1.y += v1.y; a1.z += v1.z; a1.w += v1.w;
        }
        for (; j < e; j += 6) {
            const int s = esrc[j];
            const float4 v = bf4_to_f4(*(const ushort4*)(h2 + (size_t)s * DO + c));
            a0.x += v.x; a0.y += v.y; a0.z += v.z; a0.w += v.w;
        }
    }
    float4 acc = make_float4(a0.x + a1.x, a0.y + a1.y, a0.z + a1.z, a0.w + a1.w);
    acc.x += __shfl(acc.x, lane + 30);
    acc.y += __shfl(acc.y, lane + 30);
    acc.z += __shfl(acc.z, lane + 30);
    acc.w += __shfl(acc.w, lane + 30);
    const float ax = acc.x + __shfl(acc.x, lane + 10) + __shfl(acc.x, lane + 20);
    const float ay = acc.y + __shfl(acc.y, lane + 10) + __shfl(acc.y, lane + 20);
    const float az = acc.z + __shfl(acc.z, lane + 10) + __shfl(acc.z, lane + 20);
    const float aw = acc.w + __shfl(acc.w, lane + 10) + __shfl(acc.w, lane + 20);
    if (lane < 10) {
        *(float4*)(out + (size_t)w * DO + c) = make_float4(ax, ay, az, aw);
    }
}

extern "C" void kernel_launch(void* const* d_in, const int* in_sizes, int n_in,
                              void* d_out, int out_size, void* d_ws, size_t ws_size,
                              hipStream_t stream) {
    const float* x  = (const float*)d_in[0];
    const int*   ei = (const int*)d_in[1];
    const float* W1 = (const float*)d_in[2];
    const float* W2 = (const float*)d_in[3];
    const int* src = ei;
    const int* dst = ei + NE;

    __bf16* Wf  = (__bf16*)d_ws;                     // 32768 bf16 = 64 KB
    __bf16* Wf2 = Wf + 32768;                        // 6144 bf16 = 12 KB
    __bf16* h1  = Wf2 + 6144;                        // NN*128 bf16 = 25.6 MB
    __bf16* h2  = h1 + (size_t)NN * DH;              // NN*40 bf16 = 8 MB
    unsigned* epack = (unsigned*)(h2 + (size_t)NN * DO);   // NE uint = 6.4 MB
    int* esrc   = (int*)(epack + NE);                // NE
    int* off    = esrc + NE;                         // NN+1
    int* hist2d = off + NN + 1;                      // M2
    int* offs2d = hist2d + M2;                       // M2
    int* bsum   = offs2d + M2;                       // NBS
    int* boff   = bsum + NBS;                        // NBS

    float* out = (float*)d_out;

    w1pack_kernel<<<128, 256, 0, stream>>>(W1, Wf);
    w2pack_kernel<<<24, 256, 0, stream>>>(W2, Wf2);
    gemm1_kernel<<<(NN + 63) / 64, 256, 0, stream>>>(x, Wf, h1);
    bucket_hist_kernel<<<NB_BLK, 256, 0, stream>>>(dst, hist2d);
    spart_kernel<<<NBS, 256, 0, stream>>>(hist2d, bsum);
    sblock_kernel<<<1, 64, 0, stream>>>(bsum, boff);
    sfinal_kernel<<<NBS, 256, 0, stream>>>(hist2d, boff, offs2d);
    bucket_scatter_kernel<<<NB_BLK, 256, 0, stream>>>(src, dst, offs2d, epack);
    bucket_sort_kernel<<<NB, 256, 0, stream>>>(epack, offs2d, off, esrc);
    agg1g2_kernel<<<(NN + 63) / 64, 256, 0, stream>>>(h1, esrc, off, Wf2, h2);
    agg2_kernel<<<(NN * 64 + 255) / 256, 256, 0, stream>>>(h2, esrc, off, out);
}

// Round 11
// 366.863 us; speedup vs baseline: 1.1478x; 1.1478x over previous
//
#include <hip/hip_runtime.h>

constexpr int NN = 100000;   // nodes
constexpr int NE = 1600000;  // edges
constexpr int DI = 256, DH = 128, DO = 40;

// Bucket radix sort params
constexpr int NB = (NN + 255) >> 8;        // 391 buckets of 256 dst values
constexpr int NB_BLK = 128;                // blocks in hist/scatter passes
constexpr int CHUNK = NE / NB_BLK;         // 12500 edges per block (exact)
constexpr int M2 = NB * NB_BLK;            // 50048 hist entries
constexpr int NBS = (M2 + 1023) / 1024;    // 49 scan partials
constexpr int STAGE_CAP = 6144;            // bucket staging (avg load ~4092)

typedef __attribute__((ext_vector_type(8))) __bf16 bf16x8;
typedef __attribute__((ext_vector_type(4))) float f32x4;

__device__ inline float4 bf4_to_f4(ushort4 u) {
    return make_float4(__builtin_bit_cast(float, (unsigned)u.x << 16),
                       __builtin_bit_cast(float, (unsigned)u.y << 16),
                       __builtin_bit_cast(float, (unsigned)u.z << 16),
                       __builtin_bit_cast(float, (unsigned)u.w << 16));
}
__device__ inline unsigned short f2bf(float f) {
    return __builtin_bit_cast(unsigned short, (__bf16)f);   // RNE
}
__device__ inline bf16x8 bf16x8_zero() {
    bf16x8 r;
    #pragma unroll
    for (int j = 0; j < 8; ++j) r[j] = (__bf16)0.f;
    return r;
}
__device__ inline bf16x8 load_cvt_a(const float* __restrict__ p, bool ok) {
    if (!ok) return bf16x8_zero();
    bf16x8 r;
    const float4 v0 = *(const float4*)p;
    const float4 v1 = *(const float4*)(p + 4);
    r[0] = (__bf16)v0.x; r[1] = (__bf16)v0.y; r[2] = (__bf16)v0.z; r[3] = (__bf16)v0.w;
    r[4] = (__bf16)v1.x; r[5] = (__bf16)v1.y; r[6] = (__bf16)v1.z; r[7] = (__bf16)v1.w;
    return r;
}
__device__ inline void acc4(float4& a, float4 v) {
    a.x += v.x; a.y += v.y; a.z += v.z; a.w += v.w;
}

// ---------------- Weight packs (one launch): W1 and W2 -> MFMA B-frag order -------
__global__ __launch_bounds__(256) void wpack_kernel(const float* __restrict__ W1,
                                                    const float* __restrict__ W2,
                                                    __bf16* __restrict__ Wf,
                                                    __bf16* __restrict__ Wf2) {
    if (blockIdx.x < 128) {
        const int i = blockIdx.x * 256 + threadIdx.x;   // 32768 total
        const int j = i & 7;
        const int lane = (i >> 3) & 63;
        const int nt = (i >> 9) & 7;
        const int kt = i >> 12;
        const int k = kt * 32 + (lane >> 4) * 8 + j;
        const int n = nt * 16 + (lane & 15);
        Wf[i] = (__bf16)W1[(size_t)k * DH + n];
    } else {
        const int i = (blockIdx.x - 128) * 256 + threadIdx.x;   // 6144 total
        if (i < 6144) {
            const int j = i & 7;
            const int lane = (i >> 3) & 63;
            const int g = i >> 9;          // 0..11
            const int nt = g % 3, ks = g / 3;
            const int k = ks * 32 + (lane >> 4) * 8 + j;
            const int n = nt * 16 + (lane & 15);
            Wf2[i] = (n < DO) ? (__bf16)W2[(size_t)k * DO + n] : (__bf16)0.f;
        }
    }
}

// ---------------- GEMM1 (bf16 MFMA, no LDS, no barriers) ----------------
__global__ __launch_bounds__(256) void gemm1_kernel(const float* __restrict__ x,
                                                    const __bf16* __restrict__ Wf,
                                                    __bf16* __restrict__ h1) {
    const int t = threadIdx.x;
    const int wave = t >> 6, lane = t & 63;
    const int q = lane >> 4, m = lane & 15;
    const int row0 = blockIdx.x * 64 + wave * 16;
    const int r = row0 + m;
    const bool ok = r < NN;
    const float* xp = x + (size_t)r * DI;

    bf16x8 a[8];
    #pragma unroll
    for (int kt = 0; kt < 8; ++kt)
        a[kt] = load_cvt_a(xp + kt * 32 + q * 8, ok);

    f32x4 acc[8];
    #pragma unroll
    for (int nt = 0; nt < 8; ++nt)
        #pragma unroll
        for (int rr = 0; rr < 4; ++rr) acc[nt][rr] = 0.f;

    const bf16x8* wf = (const bf16x8*)Wf;
    #pragma unroll
    for (int kt = 0; kt < 8; ++kt) {
        #pragma unroll
        for (int nt = 0; nt < 8; ++nt) {
            const bf16x8 b = wf[(kt * 8 + nt) * 64 + lane];
            acc[nt] = __builtin_amdgcn_mfma_f32_16x16x32_bf16(a[kt], b, acc[nt], 0, 0, 0);
        }
    }
    #pragma unroll
    for (int reg = 0; reg < 4; ++reg) {
        const int rr = row0 + q * 4 + reg;
        if (rr < NN) {
            __bf16* hp = h1 + (size_t)rr * DH + m;
            #pragma unroll
            for (int nt = 0; nt < 8; ++nt) hp[nt * 16] = (__bf16)acc[nt][reg];
        }
    }
}

// ---------------- P1: per-block bucket histogram ----------------
__global__ __launch_bounds__(256) void bucket_hist_kernel(const int* __restrict__ dst,
                                                          int* __restrict__ hist2d) {
    __shared__ int h[NB];
    for (int i = threadIdx.x; i < NB; i += 256) h[i] = 0;
    __syncthreads();
    const int base = blockIdx.x * CHUNK;
    for (int i = threadIdx.x; i < CHUNK; i += 256)
        atomicAdd(&h[dst[base + i] >> 8], 1);
    __syncthreads();
    for (int i = threadIdx.x; i < NB; i += 256)
        hist2d[i * NB_BLK + blockIdx.x] = h[i];   // bucket-major
}

// ---------------- scan of hist2d (M2 entries) ----------------
__global__ __launch_bounds__(256) void spart_kernel(const int* __restrict__ in,
                                                    int* __restrict__ bsum) {
    __shared__ int red[256];
    const int idx = blockIdx.x * 1024 + threadIdx.x * 4;
    int s = 0;
    if (idx < M2) { const int4 v = *(const int4*)(in + idx); s = v.x + v.y + v.z + v.w; }
    red[threadIdx.x] = s;
    __syncthreads();
    #pragma unroll
    for (int d = 128; d > 0; d >>= 1) {
        if (threadIdx.x < d) red[threadIdx.x] += red[threadIdx.x + d];
        __syncthreads();
    }
    if (threadIdx.x == 0) bsum[blockIdx.x] = red[0];
}

__global__ __launch_bounds__(64) void sblock_kernel(const int* __restrict__ bsum,
                                                    int* __restrict__ boff) {
    __shared__ int part[64];
    const int t = threadIdx.x;
    const int v = (t < NBS) ? bsum[t] : 0;
    part[t] = v;
    __syncthreads();
    for (int d = 1; d < 64; d <<= 1) {
        const int u = (t >= d) ? part[t - d] : 0;
        __syncthreads();
        part[t] += u;
        __syncthreads();
    }
    if (t < NBS) boff[t] = part[t] - v;
}

__global__ __launch_bounds__(256) void sfinal_kernel(const int* __restrict__ in,
                                                     const int* __restrict__ boff,
                                                     int* __restrict__ out) {
    __shared__ int part[256];
    const int t = threadIdx.x;
    const int idx = blockIdx.x * 1024 + t * 4;
    int4 v = make_int4(0, 0, 0, 0);
    if (idx < M2) v = *(const int4*)(in + idx);
    const int s = v.x + v.y + v.z + v.w;
    part[t] = s;
    __syncthreads();
    for (int d = 1; d < 256; d <<= 1) {
        const int u = (t >= d) ? part[t - d] : 0;
        __syncthreads();
        part[t] += u;
        __syncthreads();
    }
    if (idx < M2) {
        const int base = boff[blockIdx.x] + part[t] - s;
        *(int4*)(out + idx) = make_int4(base, base + v.x, base + v.x + v.y,
                                        base + v.x + v.y + v.z);
    }
}

// ---------------- P3: scatter packed (src | dstbyte<<24) into bucket partitions -------
__global__ __launch_bounds__(256) void bucket_scatter_kernel(const int* __restrict__ src,
                                                             const int* __restrict__ dst,
                                                             const int* __restrict__ offs2d,
                                                             unsigned* __restrict__ epack) {
    __shared__ int cur[NB];
    for (int i = threadIdx.x; i < NB; i += 256)
        cur[i] = offs2d[i * NB_BLK + blockIdx.x];
    __syncthreads();
    const int base = blockIdx.x * CHUNK;
    for (int i = threadIdx.x; i < CHUNK; i += 256) {
        const int d = dst[base + i], s = src[base + i];
        const int p = atomicAdd(&cur[d >> 8], 1);
        epack[p] = (unsigned)s | ((unsigned)(d & 255) << 24);
    }
}

// ---------------- P4: within-bucket counting sort; emits off[] and esrc ----------------
__global__ __launch_bounds__(256) void bucket_sort_kernel(const unsigned* __restrict__ epack,
                                                          const int* __restrict__ offs2d,
                                                          int* __restrict__ off,
                                                          int* __restrict__ esrc) {
    __shared__ int cnt[256];
    __shared__ int incl[256];
    __shared__ int cur[256];
    __shared__ int stage[STAGE_CAP];
    const int b = blockIdx.x;
    const int t = threadIdx.x;
    const int bstart = offs2d[b * NB_BLK];
    const int bend = (b + 1 < NB) ? offs2d[(b + 1) * NB_BLK] : NE;
    const int n = bend - bstart;
    cnt[t] = 0;
    __syncthreads();
    for (int i = t; i < n; i += 256)
        atomicAdd(&cnt[epack[bstart + i] >> 24], 1);
    __syncthreads();
    incl[t] = cnt[t];
    __syncthreads();
    for (int d = 1; d < 256; d <<= 1) {
        const int u = (t >= d) ? incl[t - d] : 0;
        __syncthreads();
        incl[t] += u;
        __syncthreads();
    }
    const int ex = incl[t] - cnt[t];   // exclusive prefix within bucket
    const int node = (b << 8) + t;
    if (node <= NN) off[node] = bstart + ex;   // node==NN -> off[NN]=NE
    cur[t] = ex;
    __syncthreads();
    const bool staged = (n <= STAGE_CAP);
    for (int i = t; i < n; i += 256) {
        const unsigned pk = epack[bstart + i];
        const int p = atomicAdd(&cur[pk >> 24], 1);
        const int s = (int)(pk & 0xFFFFFFu);
        if (staged) stage[p] = s;
        else esrc[bstart + p] = s;
    }
    __syncthreads();
    if (staged)
        for (int i = t; i < n; i += 256) esrc[bstart + i] = stage[i];
}

// ---------------- Agg1: agg[n](bf16) = relu(sum h1[src_e]), d=128 ----------------
// One wave per node. 64 edge indices loaded in one coalesced op, broadcast via
// __shfl. ALL shuffles are wave-uniform-exec: loop bounds use only (kk, cnt)
// which are wave-uniform; tail clamps the source lane and predicates only the
// accumulate (ds_bpermute reads undefined data from inactive lanes — R10 bug).
__global__ __launch_bounds__(256) void agg1_kernel(const __bf16* __restrict__ h1,
                                                   const int* __restrict__ esrc,
                                                   const int* __restrict__ off,
                                                   __bf16* __restrict__ agg) {
    const int w = (blockIdx.x * 256 + threadIdx.x) >> 6;
    if (w >= NN) return;
    const int lane = threadIdx.x & 63;
    const int half = lane >> 5;
    const int c = (lane & 31) * 4;
    const int b = off[w], e = off[w + 1];
    const int deg = e - b;
    float4 a0 = make_float4(0.f, 0.f, 0.f, 0.f);
    float4 a1 = a0, a2 = a0, a3 = a0, a4 = a0, a5 = a0, a6 = a0, a7 = a0;

    for (int base = 0; base < deg; base += 64) {
        const int cnt = min(64, deg - base);          // wave-uniform
        const int cl = cnt - 1;
        const int idx = (base + lane < deg) ? esrc[b + base + lane] : 0;
        int kk = 0;
        for (; kk + 16 <= cnt; kk += 16) {            // uniform: 8 edges/half, all valid
            const int s0 = __shfl(idx, kk + half);
            const int s1 = __shfl(idx, kk + 2 + half);
            const int s2 = __shfl(idx, kk + 4 + half);
            const int s3 = __shfl(idx, kk + 6 + half);
            const int s4 = __shfl(idx, kk + 8 + half);
            const int s5 = __shfl(idx, kk + 10 + half);
            const int s6 = __shfl(idx, kk + 12 + half);
            const int s7 = __shfl(idx, kk + 14 + half);
            acc4(a0, bf4_to_f4(*(const ushort4*)(h1 + (size_t)s0 * DH + c)));
            acc4(a1, bf4_to_f4(*(const ushort4*)(h1 + (size_t)s1 * DH + c)));
            acc4(a2, bf4_to_f4(*(const ushort4*)(h1 + (size_t)s2 * DH + c)));
            acc4(a3, bf4_to_f4(*(const ushort4*)(h1 + (size_t)s3 * DH + c)));
            acc4(a4, bf4_to_f4(*(const ushort4*)(h1 + (size_t)s4 * DH + c)));
            acc4(a5, bf4_to_f4(*(const ushort4*)(h1 + (size_t)s5 * DH + c)));
            acc4(a6, bf4_to_f4(*(const ushort4*)(h1 + (size_t)s6 * DH + c)));
            acc4(a7, bf4_to_f4(*(const ushort4*)(h1 + (size_t)s7 * DH + c)));
        }
        for (; kk + 8 <= cnt; kk += 8) {              // uniform: 4 edges/half, all valid
            const int s0 = __shfl(idx, kk + half);
            const int s1 = __shfl(idx, kk + 2 + half);
            const int s2 = __shfl(idx, kk + 4 + half);
            const int s3 = __shfl(idx, kk + 6 + half);
            acc4(a0, bf4_to_f4(*(const ushort4*)(h1 + (size_t)s0 * DH + c)));
            acc4(a1, bf4_to_f4(*(const ushort4*)(h1 + (size_t)s1 * DH + c)));
            acc4(a2, bf4_to_f4(*(const ushort4*)(h1 + (size_t)s2 * DH + c)));
            acc4(a3, bf4_to_f4(*(const ushort4*)(h1 + (size_t)s3 * DH + c)));
        }
        for (; kk < cnt; kk += 2) {                   // uniform bound; clamp + predicate
            const int ei = kk + half;
            const int s0 = __shfl(idx, (ei < cnt) ? ei : cl);
            const float4 v = bf4_to_f4(*(const ushort4*)(h1 + (size_t)s0 * DH + c));
            if (ei < cnt) acc4(a0, v);
        }
    }
    float4 acc = make_float4(a0.x + a1.x + a2.x + a3.x + a4.x + a5.x + a6.x + a7.x,
                             a0.y + a1.y + a2.y + a3.y + a4.y + a5.y + a6.y + a7.y,
                             a0.z + a1.z + a2.z + a3.z + a4.z + a5.z + a6.z + a7.z,
                             a0.w + a1.w + a2.w + a3.w + a4.w + a5.w + a6.w + a7.w);
    acc.x += __shfl_xor(acc.x, 32);
    acc.y += __shfl_xor(acc.y, 32);
    acc.z += __shfl_xor(acc.z, 32);
    acc.w += __shfl_xor(acc.w, 32);
    if (half == 0) {
        ushort4 o;
        o.x = f2bf(fmaxf(acc.x, 0.f));
        o.y = f2bf(fmaxf(acc.y, 0.f));
        o.z = f2bf(fmaxf(acc.z, 0.f));
        o.w = f2bf(fmaxf(acc.w, 0.f));
        *(ushort4*)(agg + (size_t)w * DH + c) = o;
    }
}

// ---------------- GEMM2 (bf16 MFMA, no LDS, no barriers) ----------------
__global__ __launch_bounds__(256) void gemm2_kernel(const __bf16* __restrict__ agg,
                                                    const __bf16* __restrict__ Wf2,
                                                    __bf16* __restrict__ h2) {
    const int t = threadIdx.x;
    const int wave = t >> 6, lane = t & 63;
    const int q = lane >> 4, m = lane & 15;
    const int row0 = blockIdx.x * 64 + wave * 16;
    const int r = row0 + m;
    const bool ok = r < NN;
    const __bf16* ap = agg + (size_t)r * DH;

    f32x4 acc[3];
    #pragma unroll
    for (int nt = 0; nt < 3; ++nt)
        #pragma unroll
        for (int rr = 0; rr < 4; ++rr) acc[nt][rr] = 0.f;

    const bf16x8* wf2 = (const bf16x8*)Wf2;
    #pragma unroll
    for (int ks = 0; ks < 4; ++ks) {
        const int k0 = ks * 32 + q * 8;
        const bf16x8 a = ok ? *(const bf16x8*)(ap + k0) : bf16x8_zero();
        #pragma unroll
        for (int nt = 0; nt < 3; ++nt) {
            const bf16x8 b = wf2[(ks * 3 + nt) * 64 + lane];
            acc[nt] = __builtin_amdgcn_mfma_f32_16x16x32_bf16(a, b, acc[nt], 0, 0, 0);
        }
    }
    #pragma unroll
    for (int reg = 0; reg < 4; ++reg) {
        const int rr = row0 + q * 4 + reg;
        if (rr < NN) {
            #pragma unroll
            for (int nt = 0; nt < 3; ++nt) {
                const int cc = nt * 16 + m;
                if (cc < DO) h2[(size_t)rr * DO + cc] = (__bf16)acc[nt][reg];
            }
        }
    }
}

// ---------------- Agg2: out[n](f32) = sum h2[src_e], d=40 ----------------
// Same uniform-exec broadcast discipline: every __shfl clamped to [0,cnt-1] and
// executed by all 64 lanes; only the accumulates are predicated. Idle lanes
// (sub==6) keep zero accumulators so the cross-sub reduce stays exact.
__global__ __launch_bounds__(256) void agg2_kernel(const __bf16* __restrict__ h2,
                                                   const int* __restrict__ esrc,
                                                   const int* __restrict__ off,
                                                   float* __restrict__ out) {
    const int w = (blockIdx.x * 256 + threadIdx.x) >> 6;
    if (w >= NN) return;
    const int lane = threadIdx.x & 63;
    const int sub = lane / 10;          // 0..5 active, 6 for lanes 60..63
    const int c = (lane % 10) * 4;
    const int b = off[w], e = off[w + 1];
    const int deg = e - b;
    float4 a0 = make_float4(0.f, 0.f, 0.f, 0.f);
    float4 a1 = a0, a2 = a0, a3 = a0;

    for (int base = 0; base < deg; base += 64) {
        const int cnt = min(64, deg - base);          // wave-uniform
        const int cl = cnt - 1;
        const int idx = (base + lane < deg) ? esrc[b + base + lane] : 0;
        const bool act = sub < 6;
        int kk = 0;
        for (; kk + 24 <= cnt; kk += 24) {            // uniform: 4 edges/sub
            const int e0 = kk + sub;
            const int s0 = __shfl(idx, min(e0, cl));
            const int s1 = __shfl(idx, min(e0 + 6, cl));
            const int s2 = __shfl(idx, min(e0 + 12, cl));
            const int s3 = __shfl(idx, min(e0 + 18, cl));
            const float4 v0 = bf4_to_f4(*(const ushort4*)(h2 + (size_t)s0 * DO + c));
            const float4 v1 = bf4_to_f4(*(const ushort4*)(h2 + (size_t)s1 * DO + c));
            const float4 v2 = bf4_to_f4(*(const ushort4*)(h2 + (size_t)s2 * DO + c));
            const float4 v3 = bf4_to_f4(*(const ushort4*)(h2 + (size_t)s3 * DO + c));
            if (act) { acc4(a0, v0); acc4(a1, v1); acc4(a2, v2); acc4(a3, v3); }
        }
        for (; kk + 12 <= cnt; kk += 12) {            // uniform: 2 edges/sub
            const int e0 = kk + sub;
            const int s0 = __shfl(idx, min(e0, cl));
            const int s1 = __shfl(idx, min(e0 + 6, cl));
            const float4 v0 = bf4_to_f4(*(const ushort4*)(h2 + (size_t)s0 * DO + c));
            const float4 v1 = bf4_to_f4(*(const ushort4*)(h2 + (size_t)s1 * DO + c));
            if (act) { acc4(a0, v0); acc4(a1, v1); }
        }
        for (; kk < cnt; kk += 6) {                   // uniform bound; clamp + predicate
            const int e0 = kk + sub;
            const int s0 = __shfl(idx, min(e0, cl));
            const float4 v = bf4_to_f4(*(const ushort4*)(h2 + (size_t)s0 * DO + c));
            if (act && e0 < cnt) acc4(a0, v);
        }
    }
    float4 acc = make_float4(a0.x + a1.x + a2.x + a3.x, a0.y + a1.y + a2.y + a3.y,
                             a0.z + a1.z + a2.z + a3.z, a0.w + a1.w + a2.w + a3.w);
    acc.x += __shfl(acc.x, lane + 30);
    acc.y += __shfl(acc.y, lane + 30);
    acc.z += __shfl(acc.z, lane + 30);
    acc.w += __shfl(acc.w, lane + 30);
    const float ax = acc.x + __shfl(acc.x, lane + 10) + __shfl(acc.x, lane + 20);
    const float ay = acc.y + __shfl(acc.y, lane + 10) + __shfl(acc.y, lane + 20);
    const float az = acc.z + __shfl(acc.z, lane + 10) + __shfl(acc.z, lane + 20);
    const float aw = acc.w + __shfl(acc.w, lane + 10) + __shfl(acc.w, lane + 20);
    if (lane < 10) {
        *(float4*)(out + (size_t)w * DO + c) = make_float4(ax, ay, az, aw);
    }
}

extern "C" void kernel_launch(void* const* d_in, const int* in_sizes, int n_in,
                              void* d_out, int out_size, void* d_ws, size_t ws_size,
                              hipStream_t stream) {
    const float* x  = (const float*)d_in[0];
    const int*   ei = (const int*)d_in[1];
    const float* W1 = (const float*)d_in[2];
    const float* W2 = (const float*)d_in[3];
    const int* src = ei;
    const int* dst = ei + NE;

    __bf16* Wf  = (__bf16*)d_ws;                     // 32768 bf16 = 64 KB
    __bf16* Wf2 = Wf + 32768;                        // 6144 bf16 = 12 KB
    __bf16* h1  = Wf2 + 6144;                        // NN*128 bf16 = 25.6 MB
    __bf16* agg = h1 + (size_t)NN * DH;              // NN*128 bf16 = 25.6 MB
    __bf16* h2  = h1;                                // NN*40 bf16 (aliases h1; dead after agg1)
    unsigned* epack = (unsigned*)(agg + (size_t)NN * DH);  // NE uint = 6.4 MB
    int* esrc   = (int*)(epack + NE);                // NE
    int* off    = esrc + NE;                         // NN+1
    int* hist2d = off + NN + 1;                      // M2
    int* offs2d = hist2d + M2;                       // M2
    int* bsum   = offs2d + M2;                       // NBS
    int* boff   = bsum + NBS;                        // NBS

    float* out = (float*)d_out;

    wpack_kernel<<<152, 256, 0, stream>>>(W1, W2, Wf, Wf2);
    gemm1_kernel<<<(NN + 63) / 64, 256, 0, stream>>>(x, Wf, h1);
    bucket_hist_kernel<<<NB_BLK, 256, 0, stream>>>(dst, hist2d);
    spart_kernel<<<NBS, 256, 0, stream>>>(hist2d, bsum);
    sblock_kernel<<<1, 64, 0, stream>>>(bsum, boff);
    sfinal_kernel<<<NBS, 256, 0, stream>>>(hist2d, boff, offs2d);
    bucket_scatter_kernel<<<NB_BLK, 256, 0, stream>>>(src, dst, offs2d, epack);
    bucket_sort_kernel<<<NB, 256, 0, stream>>>(epack, offs2d, off, esrc);
    agg1_kernel<<<(NN * 64 + 255) / 256, 256, 0, stream>>>(h1, esrc, off, agg);
    gemm2_kernel<<<(NN + 63) / 64, 256, 0, stream>>>(agg, Wf2, h2);
    agg2_kernel<<<(NN * 64 + 255) / 256, 256, 0, stream>>>(h2, esrc, off, out);
}

// Round 12
// 354.783 us; speedup vs baseline: 1.1869x; 1.0340x over previous
//
#include <hip/hip_runtime.h>

constexpr int NN = 100000;   // nodes
constexpr int NE = 1600000;  // edges
constexpr int DI = 256, DH = 128, DO = 40;

// Bucket radix sort params
constexpr int NB = (NN + 255) >> 8;        // 391 buckets of 256 dst values
constexpr int NB_BLK = 128;                // blocks in hist/scatter passes
constexpr int CHUNK = NE / NB_BLK;         // 12500 edges per block (exact)
constexpr int M2 = NB * NB_BLK;            // 50048 hist entries
constexpr int NBS = (M2 + 1023) / 1024;    // 49 scan blocks
constexpr int STAGE_CAP = 6144;            // bucket staging (avg load ~4092)
constexpr int WPACK_BLOCKS = 152;          // 128 (W1) + 24 (W2)
constexpr int GEMM1_BLOCKS = (NN + 63) / 64;   // 1563

typedef __attribute__((ext_vector_type(8))) __bf16 bf16x8;
typedef __attribute__((ext_vector_type(4))) float f32x4;

__device__ inline float4 bf4_to_f4(ushort4 u) {
    return make_float4(__builtin_bit_cast(float, (unsigned)u.x << 16),
                       __builtin_bit_cast(float, (unsigned)u.y << 16),
                       __builtin_bit_cast(float, (unsigned)u.z << 16),
                       __builtin_bit_cast(float, (unsigned)u.w << 16));
}
__device__ inline unsigned short f2bf(float f) {
    return __builtin_bit_cast(unsigned short, (__bf16)f);   // RNE
}
__device__ inline bf16x8 bf16x8_zero() {
    bf16x8 r;
    #pragma unroll
    for (int j = 0; j < 8; ++j) r[j] = (__bf16)0.f;
    return r;
}
__device__ inline bf16x8 load_cvt_a(const float* __restrict__ p, bool ok) {
    if (!ok) return bf16x8_zero();
    bf16x8 r;
    const float4 v0 = *(const float4*)p;
    const float4 v1 = *(const float4*)(p + 4);
    r[0] = (__bf16)v0.x; r[1] = (__bf16)v0.y; r[2] = (__bf16)v0.z; r[3] = (__bf16)v0.w;
    r[4] = (__bf16)v1.x; r[5] = (__bf16)v1.y; r[6] = (__bf16)v1.z; r[7] = (__bf16)v1.w;
    return r;
}
__device__ inline void acc4(float4& a, float4 v) {
    a.x += v.x; a.y += v.y; a.z += v.z; a.w += v.w;
}

// ---------------- K1: wpack (blocks 0..151)  ||  bucket histogram (152..279) -------
__global__ __launch_bounds__(256) void wpack_hist_kernel(const float* __restrict__ W1,
                                                         const float* __restrict__ W2,
                                                         const int* __restrict__ dst,
                                                         __bf16* __restrict__ Wf,
                                                         __bf16* __restrict__ Wf2,
                                                         int* __restrict__ hist2d) {
    __shared__ int h[NB];
    if (blockIdx.x < 128) {
        const int i = blockIdx.x * 256 + threadIdx.x;   // 32768 total
        const int j = i & 7;
        const int lane = (i >> 3) & 63;
        const int nt = (i >> 9) & 7;
        const int kt = i >> 12;
        const int k = kt * 32 + (lane >> 4) * 8 + j;
        const int n = nt * 16 + (lane & 15);
        Wf[i] = (__bf16)W1[(size_t)k * DH + n];
    } else if (blockIdx.x < WPACK_BLOCKS) {
        const int i = (blockIdx.x - 128) * 256 + threadIdx.x;   // 6144 total
        if (i < 6144) {
            const int j = i & 7;
            const int lane = (i >> 3) & 63;
            const int g = i >> 9;          // 0..11
            const int nt = g % 3, ks = g / 3;
            const int k = ks * 32 + (lane >> 4) * 8 + j;
            const int n = nt * 16 + (lane & 15);
            Wf2[i] = (n < DO) ? (__bf16)W2[(size_t)k * DO + n] : (__bf16)0.f;
        }
    } else {
        const int hb = blockIdx.x - WPACK_BLOCKS;       // 0..127
        for (int i = threadIdx.x; i < NB; i += 256) h[i] = 0;
        __syncthreads();
        const int base = hb * CHUNK;
        for (int i = threadIdx.x; i < CHUNK; i += 256)
            atomicAdd(&h[dst[base + i] >> 8], 1);
        __syncthreads();
        for (int i = threadIdx.x; i < NB; i += 256)
            hist2d[i * NB_BLK + hb] = h[i];             // bucket-major
    }
}

// ---------------- K2: gemm1 (blocks 0..1562)  ||  one-kernel scan (1563..1611) -----
// Scan: block b redundantly sums hist2d[0 .. b*1024) for its prefix base (L2-fast),
// then scans its own 1024-entry chunk. Replaces 3 launches.
__global__ __launch_bounds__(256) void gemm1_scan_kernel(const float* __restrict__ x,
                                                         const __bf16* __restrict__ Wf,
                                                         __bf16* __restrict__ h1,
                                                         const int* __restrict__ hist2d,
                                                         int* __restrict__ offs2d) {
    __shared__ int red[256];
    if (blockIdx.x < GEMM1_BLOCKS) {
        const int t = threadIdx.x;
        const int wave = t >> 6, lane = t & 63;
        const int q = lane >> 4, m = lane & 15;
        const int row0 = blockIdx.x * 64 + wave * 16;
        const int r = row0 + m;
        const bool ok = r < NN;
        const float* xp = x + (size_t)r * DI;

        bf16x8 a[8];
        #pragma unroll
        for (int kt = 0; kt < 8; ++kt)
            a[kt] = load_cvt_a(xp + kt * 32 + q * 8, ok);

        f32x4 acc[8];
        #pragma unroll
        for (int nt = 0; nt < 8; ++nt)
            #pragma unroll
            for (int rr = 0; rr < 4; ++rr) acc[nt][rr] = 0.f;

        const bf16x8* wf = (const bf16x8*)Wf;
        #pragma unroll
        for (int kt = 0; kt < 8; ++kt) {
            #pragma unroll
            for (int nt = 0; nt < 8; ++nt) {
                const bf16x8 b = wf[(kt * 8 + nt) * 64 + lane];
                acc[nt] = __builtin_amdgcn_mfma_f32_16x16x32_bf16(a[kt], b, acc[nt], 0, 0, 0);
            }
        }
        #pragma unroll
        for (int reg = 0; reg < 4; ++reg) {
            const int rr = row0 + q * 4 + reg;
            if (rr < NN) {
                __bf16* hp = h1 + (size_t)rr * DH + m;
                #pragma unroll
                for (int nt = 0; nt < 8; ++nt) hp[nt * 16] = (__bf16)acc[nt][reg];
            }
        }
    } else {
        const int b = blockIdx.x - GEMM1_BLOCKS;    // 0..NBS-1
        const int t = threadIdx.x;
        // prefix base = sum of hist2d[0 .. b*1024)
        int s = 0;
        const int limit = b * 1024;
        for (int i = t * 4; i < limit; i += 1024) {
            const int4 v = *(const int4*)(hist2d + i);
            s += v.x + v.y + v.z + v.w;
        }
        red[t] = s;
        __syncthreads();
        #pragma unroll
        for (int d = 128; d > 0; d >>= 1) {
            if (t < d) red[t] += red[t + d];
            __syncthreads();
        }
        const int base = red[0];
        __syncthreads();
        // own chunk scan
        const int idx = b * 1024 + t * 4;
        int4 v = make_int4(0, 0, 0, 0);
        if (idx < M2) v = *(const int4*)(hist2d + idx);
        const int sl = v.x + v.y + v.z + v.w;
        red[t] = sl;
        __syncthreads();
        for (int d = 1; d < 256; d <<= 1) {
            const int u = (t >= d) ? red[t - d] : 0;
            __syncthreads();
            red[t] += u;
            __syncthreads();
        }
        if (idx < M2) {
            const int e0 = base + red[t] - sl;
            *(int4*)(offs2d + idx) = make_int4(e0, e0 + v.x, e0 + v.x + v.y,
                                               e0 + v.x + v.y + v.z);
        }
    }
}

// ---------------- P3: scatter packed (src | dstbyte<<24) into bucket partitions -------
__global__ __launch_bounds__(256) void bucket_scatter_kernel(const int* __restrict__ src,
                                                             const int* __restrict__ dst,
                                                             const int* __restrict__ offs2d,
                                                             unsigned* __restrict__ epack) {
    __shared__ int cur[NB];
    for (int i = threadIdx.x; i < NB; i += 256)
        cur[i] = offs2d[i * NB_BLK + blockIdx.x];
    __syncthreads();
    const int base = blockIdx.x * CHUNK;
    for (int i = threadIdx.x; i < CHUNK; i += 256) {
        const int d = dst[base + i], s = src[base + i];
        const int p = atomicAdd(&cur[d >> 8], 1);
        epack[p] = (unsigned)s | ((unsigned)(d & 255) << 24);
    }
}

// ---------------- P4: within-bucket counting sort; emits off[] and esrc ----------------
__global__ __launch_bounds__(256) void bucket_sort_kernel(const unsigned* __restrict__ epack,
                                                          const int* __restrict__ offs2d,
                                                          int* __restrict__ off,
                                                          int* __restrict__ esrc) {
    __shared__ int cnt[256];
    __shared__ int incl[256];
    __shared__ int cur[256];
    __shared__ int stage[STAGE_CAP];
    const int b = blockIdx.x;
    const int t = threadIdx.x;
    const int bstart = offs2d[b * NB_BLK];
    const int bend = (b + 1 < NB) ? offs2d[(b + 1) * NB_BLK] : NE;
    const int n = bend - bstart;
    cnt[t] = 0;
    __syncthreads();
    for (int i = t; i < n; i += 256)
        atomicAdd(&cnt[epack[bstart + i] >> 24], 1);
    __syncthreads();
    incl[t] = cnt[t];
    __syncthreads();
    for (int d = 1; d < 256; d <<= 1) {
        const int u = (t >= d) ? incl[t - d] : 0;
        __syncthreads();
        incl[t] += u;
        __syncthreads();
    }
    const int ex = incl[t] - cnt[t];   // exclusive prefix within bucket
    const int node = (b << 8) + t;
    if (node <= NN) off[node] = bstart + ex;   // node==NN -> off[NN]=NE
    cur[t] = ex;
    __syncthreads();
    const bool staged = (n <= STAGE_CAP);
    for (int i = t; i < n; i += 256) {
        const unsigned pk = epack[bstart + i];
        const int p = atomicAdd(&cur[pk >> 24], 1);
        const int s = (int)(pk & 0xFFFFFFu);
        if (staged) stage[p] = s;
        else esrc[bstart + p] = s;
    }
    __syncthreads();
    if (staged)
        for (int i = t; i < n; i += 256) esrc[bstart + i] = stage[i];
}

// ---------------- Agg1 (R8 version): agg[n](bf16) = relu(sum h1[src_e]), d=128 --------
// Half-wave per edge (32 lanes x ushort4 = one 256B row); unroll 4 -> 8 loads in flight.
// [R11 broadcast variant measured slower: VGPR 24->44, occ 70->44, dur 67->72. Reverted.]
__global__ __launch_bounds__(256) void agg1_kernel(const __bf16* __restrict__ h1,
                                                   const int* __restrict__ esrc,
                                                   const int* __restrict__ off,
                                                   __bf16* __restrict__ agg) {
    const int w = (blockIdx.x * 256 + threadIdx.x) >> 6;
    if (w >= NN) return;
    const int lane = threadIdx.x & 63;
    const int half = lane >> 5;
    const int c = (lane & 31) * 4;
    const int b = off[w], e = off[w + 1];
    float4 a0 = make_float4(0.f, 0.f, 0.f, 0.f);
    float4 a1 = a0, a2 = a0, a3 = a0;
    int j = b + half;
    for (; j + 6 < e; j += 8) {
        const int s0 = esrc[j], s1 = esrc[j + 2], s2 = esrc[j + 4], s3 = esrc[j + 6];
        acc4(a0, bf4_to_f4(*(const ushort4*)(h1 + (size_t)s0 * DH + c)));
        acc4(a1, bf4_to_f4(*(const ushort4*)(h1 + (size_t)s1 * DH + c)));
        acc4(a2, bf4_to_f4(*(const ushort4*)(h1 + (size_t)s2 * DH + c)));
        acc4(a3, bf4_to_f4(*(const ushort4*)(h1 + (size_t)s3 * DH + c)));
    }
    for (; j < e; j += 2) {
        const int s = esrc[j];
        acc4(a0, bf4_to_f4(*(const ushort4*)(h1 + (size_t)s * DH + c)));
    }
    float4 acc = make_float4(a0.x + a1.x + a2.x + a3.x,
                             a0.y + a1.y + a2.y + a3.y,
                             a0.z + a1.z + a2.z + a3.z,
                             a0.w + a1.w + a2.w + a3.w);
    acc.x += __shfl_xor(acc.x, 32);
    acc.y += __shfl_xor(acc.y, 32);
    acc.z += __shfl_xor(acc.z, 32);
    acc.w += __shfl_xor(acc.w, 32);
    if (half == 0) {
        ushort4 o;
        o.x = f2bf(fmaxf(acc.x, 0.f));
        o.y = f2bf(fmaxf(acc.y, 0.f));
        o.z = f2bf(fmaxf(acc.z, 0.f));
        o.w = f2bf(fmaxf(acc.w, 0.f));
        *(ushort4*)(agg + (size_t)w * DH + c) = o;
    }
}

// ---------------- GEMM2 (bf16 MFMA, no LDS, no barriers) ----------------
__global__ __launch_bounds__(256) void gemm2_kernel(const __bf16* __restrict__ agg,
                                                    const __bf16* __restrict__ Wf2,
                                                    __bf16* __restrict__ h2) {
    const int t = threadIdx.x;
    const int wave = t >> 6, lane = t & 63;
    const int q = lane >> 4, m = lane & 15;
    const int row0 = blockIdx.x * 64 + wave * 16;
    const int r = row0 + m;
    const bool ok = r < NN;
    const __bf16* ap = agg + (size_t)r * DH;

    f32x4 acc[3];
    #pragma unroll
    for (int nt = 0; nt < 3; ++nt)
        #pragma unroll
        for (int rr = 0; rr < 4; ++rr) acc[nt][rr] = 0.f;

    const bf16x8* wf2 = (const bf16x8*)Wf2;
    #pragma unroll
    for (int ks = 0; ks < 4; ++ks) {
        const int k0 = ks * 32 + q * 8;
        const bf16x8 a = ok ? *(const bf16x8*)(ap + k0) : bf16x8_zero();
        #pragma unroll
        for (int nt = 0; nt < 3; ++nt) {
            const bf16x8 b = wf2[(ks * 3 + nt) * 64 + lane];
            acc[nt] = __builtin_amdgcn_mfma_f32_16x16x32_bf16(a, b, acc[nt], 0, 0, 0);
        }
    }
    #pragma unroll
    for (int reg = 0; reg < 4; ++reg) {
        const int rr = row0 + q * 4 + reg;
        if (rr < NN) {
            #pragma unroll
            for (int nt = 0; nt < 3; ++nt) {
                const int cc = nt * 16 + m;
                if (cc < DO) h2[(size_t)rr * DO + cc] = (__bf16)acc[nt][reg];
            }
        }
    }
}

// ---------------- Agg2 (R11 version): out[n](f32) = sum h2[src_e], d=40 ---------------
// Index-broadcast with uniform-exec shuffles (clamped sources, predicated adds).
__global__ __launch_bounds__(256) void agg2_kernel(const __bf16* __restrict__ h2,
                                                   const int* __restrict__ esrc,
                                                   const int* __restrict__ off,
                                                   float* __restrict__ out) {
    const int w = (blockIdx.x * 256 + threadIdx.x) >> 6;
    if (w >= NN) return;
    const int lane = threadIdx.x & 63;
    const int sub = lane / 10;          // 0..5 active, 6 for lanes 60..63
    const int c = (lane % 10) * 4;
    const int b = off[w], e = off[w + 1];
    const int deg = e - b;
    float4 a0 = make_float4(0.f, 0.f, 0.f, 0.f);
    float4 a1 = a0, a2 = a0, a3 = a0;

    for (int base = 0; base < deg; base += 64) {
        const int cnt = min(64, deg - base);          // wave-uniform
        const int cl = cnt - 1;
        const int idx = (base + lane < deg) ? esrc[b + base + lane] : 0;
        const bool act = sub < 6;
        int kk = 0;
        for (; kk + 24 <= cnt; kk += 24) {            // uniform: 4 edges/sub
            const int e0 = kk + sub;
            const int s0 = __shfl(idx, min(e0, cl));
            const int s1 = __shfl(idx, min(e0 + 6, cl));
            const int s2 = __shfl(idx, min(e0 + 12, cl));
            const int s3 = __shfl(idx, min(e0 + 18, cl));
            const float4 v0 = bf4_to_f4(*(const ushort4*)(h2 + (size_t)s0 * DO + c));
            const float4 v1 = bf4_to_f4(*(const ushort4*)(h2 + (size_t)s1 * DO + c));
            const float4 v2 = bf4_to_f4(*(const ushort4*)(h2 + (size_t)s2 * DO + c));
            const float4 v3 = bf4_to_f4(*(const ushort4*)(h2 + (size_t)s3 * DO + c));
            if (act) { acc4(a0, v0); acc4(a1, v1); acc4(a2, v2); acc4(a3, v3); }
        }
        for (; kk + 12 <= cnt; kk += 12) {            // uniform: 2 edges/sub
            const int e0 = kk + sub;
            const int s0 = __shfl(idx, min(e0, cl));
            const int s1 = __shfl(idx, min(e0 + 6, cl));
            const float4 v0 = bf4_to_f4(*(const ushort4*)(h2 + (size_t)s0 * DO + c));
            const float4 v1 = bf4_to_f4(*(const ushort4*)(h2 + (size_t)s1 * DO + c));
            if (act) { acc4(a0, v0); acc4(a1, v1); }
        }
        for (; kk < cnt; kk += 6) {                   // uniform bound; clamp + predicate
            const int e0 = kk + sub;
            const int s0 = __shfl(idx, min(e0, cl));
            const float4 v = bf4_to_f4(*(const ushort4*)(h2 + (size_t)s0 * DO + c));
            if (act && e0 < cnt) acc4(a0, v);
        }
    }
    float4 acc = make_float4(a0.x + a1.x + a2.x + a3.x, a0.y + a1.y + a2.y + a3.y,
                             a0.z + a1.z + a2.z + a3.z, a0.w + a1.w + a2.w + a3.w);
    acc.x += __shfl(acc.x, lane + 30);
    acc.y += __shfl(acc.y, lane + 30);
    acc.z += __shfl(acc.z, lane + 30);
    acc.w += __shfl(acc.w, lane + 30);
    const float ax = acc.x + __shfl(acc.x, lane + 10) + __shfl(acc.x, lane + 20);
    const float ay = acc.y + __shfl(acc.y, lane + 10) + __shfl(acc.y, lane + 20);
    const float az = acc.z + __shfl(acc.z, lane + 10) + __shfl(acc.z, lane + 20);
    const float aw = acc.w + __shfl(acc.w, lane + 10) + __shfl(acc.w, lane + 20);
    if (lane < 10) {
        *(float4*)(out + (size_t)w * DO + c) = make_float4(ax, ay, az, aw);
    }
}

extern "C" void kernel_launch(void* const* d_in, const int* in_sizes, int n_in,
                              void* d_out, int out_size, void* d_ws, size_t ws_size,
                              hipStream_t stream) {
    const float* x  = (const float*)d_in[0];
    const int*   ei = (const int*)d_in[1];
    const float* W1 = (const float*)d_in[2];
    const float* W2 = (const float*)d_in[3];
    const int* src = ei;
    const int* dst = ei + NE;

    __bf16* Wf  = (__bf16*)d_ws;                     // 32768 bf16 = 64 KB
    __bf16* Wf2 = Wf + 32768;                        // 6144 bf16 = 12 KB
    __bf16* h1  = Wf2 + 6144;                        // NN*128 bf16 = 25.6 MB
    __bf16* agg = h1 + (size_t)NN * DH;              // NN*128 bf16 = 25.6 MB
    __bf16* h2  = h1;                                // NN*40 bf16 (aliases h1; dead after agg1)
    unsigned* epack = (unsigned*)(agg + (size_t)NN * DH);  // NE uint = 6.4 MB
    int* esrc   = (int*)(epack + NE);                // NE
    int* off    = esrc + NE;                         // NN+1
    int* hist2d = off + NN + 1;                      // M2
    int* offs2d = hist2d + M2;                       // M2

    float* out = (float*)d_out;

    wpack_hist_kernel<<<WPACK_BLOCKS + NB_BLK, 256, 0, stream>>>(W1, W2, dst, Wf, Wf2, hist2d);
    gemm1_scan_kernel<<<GEMM1_BLOCKS + NBS, 256, 0, stream>>>(x, Wf, h1, hist2d, offs2d);
    bucket_scatter_kernel<<<NB_BLK, 256, 0, stream>>>(src, dst, offs2d, epack);
    bucket_sort_kernel<<<NB, 256, 0, stream>>>(epack, offs2d, off, esrc);
    agg1_kernel<<<(NN * 64 + 255) / 256, 256, 0, stream>>>(h1, esrc, off, agg);
    gemm2_kernel<<<(NN + 63) / 64, 256, 0, stream>>>(agg, Wf2, h2);
    agg2_kernel<<<(NN * 64 + 255) / 256, 256, 0, stream>>>(h2, esrc, off, out);
}